// Round 1
// baseline (718.056 us; speedup 1.0000x reference)
//
#include <hip/hip_runtime.h>
#include <stdint.h>
#include <stddef.h>

#define B_ROWS 16384
#define DIN 1024
#define DOUT 1024
#define KDIM 2048   // DIN + DOUT

#define BM 128
#define BN 128
#define BK 64

typedef __bf16 bf16x8 __attribute__((ext_vector_type(8)));
typedef float floatx4 __attribute__((ext_vector_type(4)));

__device__ __forceinline__ unsigned short f2bf(float f) {
  unsigned int u = __float_as_uint(f);
  u += 0x7fffu + ((u >> 16) & 1u);   // round-to-nearest-even
  return (unsigned short)(u >> 16);
}

__device__ __forceinline__ void async16(const void* g, void* l) {
  __builtin_amdgcn_global_load_lds(
      (__attribute__((address_space(1))) void*)(g),
      (__attribute__((address_space(3))) void*)(l), 16, 0, 0);
}

__device__ __forceinline__ float sigmoid_f(float x) {
  return 1.0f / (1.0f + __expf(-x));
}
__device__ __forceinline__ float tanh_f(float x) {
  return 2.0f / (1.0f + __expf(-2.0f * x)) - 1.0f;
}

// ---- cast & concat X = [inputs | hist] -> bf16, row-major 16384 x 2048 ----
__global__ void cast_x_kernel(const float* __restrict__ inp,
                              const float* __restrict__ hist,
                              unsigned short* __restrict__ xb) {
  int idx = blockIdx.x * blockDim.x + threadIdx.x;  // one float4 per thread
  const int per = B_ROWS * DIN / 4;                 // 4,194,304
  const float* src;
  int colOff;
  int i = idx;
  if (i < per) { src = inp; colOff = 0; }
  else         { src = hist; colOff = DIN; i -= per; }
  int e = i * 4;
  int row = e >> 10;     // / 1024
  int col = e & 1023;
  const float4 v = *(const float4*)(src + (size_t)row * 1024 + col);
  ushort4 o;
  o.x = f2bf(v.x); o.y = f2bf(v.y); o.z = f2bf(v.z); o.w = f2bf(v.w);
  *(ushort4*)(xb + (size_t)row * KDIM + colOff + col) = o;
}

// ---- cast & transpose weights: Wt[g][n][k] = W_g[k][n], bf16 ----
// z = 2*g + part ; part0 = Wx (k in 0..1023), part1 = Wh (k in 1024..2047)
__global__ void transpose_cast_kernel(
    const float* __restrict__ s0, const float* __restrict__ s1,
    const float* __restrict__ s2, const float* __restrict__ s3,
    const float* __restrict__ s4, const float* __restrict__ s5,
    const float* __restrict__ s6, const float* __restrict__ s7,
    unsigned short* __restrict__ wt) {
  __shared__ float tile[32][33];
  const int z = blockIdx.z;
  const float* src;
  switch (z) {
    case 0: src = s0; break; case 1: src = s1; break;
    case 2: src = s2; break; case 3: src = s3; break;
    case 4: src = s4; break; case 5: src = s5; break;
    case 6: src = s6; break; default: src = s7; break;
  }
  const int g = z >> 1, part = z & 1;
  unsigned short* dst = wt + (size_t)g * DOUT * KDIM + (size_t)part * DIN;
  const int tx = threadIdx.x, ty = threadIdx.y;   // 32 x 8
  const int n0 = blockIdx.x * 32, k0 = blockIdx.y * 32;
#pragma unroll
  for (int j = 0; j < 32; j += 8)
    tile[ty + j][tx] = src[(size_t)(k0 + ty + j) * DOUT + n0 + tx];
  __syncthreads();
#pragma unroll
  for (int j = 0; j < 32; j += 8)
    dst[(size_t)(n0 + ty + j) * KDIM + k0 + tx] = f2bf(tile[tx][ty + j]);
}

// ---- fused 4-gate GEMM + LSTM epilogue ----
__global__ __launch_bounds__(256, 2) void lstm_fused_kernel(
    const unsigned short* __restrict__ Xb,   // 16384 x 2048 bf16
    const unsigned short* __restrict__ Wt,   // 4 x (1024 x 2048) bf16, [g][n][k]
    const float* __restrict__ b_f, const float* __restrict__ b_i,
    const float* __restrict__ b_o, const float* __restrict__ b_c,
    const int* __restrict__ carousel,
    float* __restrict__ out) {               // h (16384x1024) then c
  __shared__ unsigned short As[BM * BK];
  __shared__ unsigned short Bs[BN * BK];

  const int tid  = threadIdx.x;
  const int lane = tid & 63;
  const int wave = tid >> 6;
  const int wm   = (wave >> 1) * 64;
  const int wn   = (wave & 1) * 64;
  const int m16  = lane & 15;
  const int quad = lane >> 4;
  const int bm   = blockIdx.y * BM;
  const int bn   = blockIdx.x * BN;

  const float cf = (float)carousel[0];

  floatx4 R[4][4];
#pragma unroll
  for (int mi = 0; mi < 4; ++mi)
#pragma unroll
    for (int ni = 0; ni < 4; ++ni)
      R[mi][ni] = (floatx4){0.f, 0.f, 0.f, 0.f};

  // gate memory index: f=0, i=1, o=2, c=3 ; process order: c, i, f, o
  const int gates[4] = {3, 1, 0, 2};
  const float* bptrs[4] = {b_c, b_i, b_f, b_o};

#pragma unroll
  for (int gi = 0; gi < 4; ++gi) {
    const int g = gates[gi];
    const unsigned short* W = Wt + (size_t)g * (DOUT * KDIM);

    floatx4 acc[4][4];
#pragma unroll
    for (int mi = 0; mi < 4; ++mi)
#pragma unroll
      for (int ni = 0; ni < 4; ++ni)
        acc[mi][ni] = (floatx4){0.f, 0.f, 0.f, 0.f};

    for (int kt = 0; kt < KDIM; kt += BK) {
#pragma unroll
      for (int j = 0; j < 4; ++j) {
        const int c = j * 256 + tid;
        const int row = c >> 3;
        const int cir = c & 7;
        async16(Xb + (size_t)(bm + row) * KDIM + kt + cir * 8, As + c * 8);
      }
#pragma unroll
      for (int j = 0; j < 4; ++j) {
        const int c = j * 256 + tid;
        const int row = c >> 3;
        const int cir = c & 7;
        async16(W + (size_t)(bn + row) * KDIM + kt + cir * 8, Bs + c * 8);
      }
      __syncthreads();
#pragma unroll
      for (int kk = 0; kk < 2; ++kk) {
        bf16x8 av[4], bv[4];
#pragma unroll
        for (int mi = 0; mi < 4; ++mi)
          av[mi] = *(const bf16x8*)(As + (wm + mi * 16 + m16) * BK + kk * 32 + quad * 8);
#pragma unroll
        for (int ni = 0; ni < 4; ++ni)
          bv[ni] = *(const bf16x8*)(Bs + (wn + ni * 16 + m16) * BK + kk * 32 + quad * 8);
#pragma unroll
        for (int mi = 0; mi < 4; ++mi)
#pragma unroll
          for (int ni = 0; ni < 4; ++ni)
            acc[mi][ni] = __builtin_amdgcn_mfma_f32_16x16x32_bf16(
                av[mi], bv[ni], acc[mi][ni], 0, 0, 0);
      }
      __syncthreads();
    }

    // epilogue for this gate
    const float* bp = bptrs[gi];
    float bias[4];
#pragma unroll
    for (int ni = 0; ni < 4; ++ni) bias[ni] = bp[bn + wn + ni * 16 + m16];

#pragma unroll
    for (int mi = 0; mi < 4; ++mi) {
#pragma unroll
      for (int ni = 0; ni < 4; ++ni) {
#pragma unroll
        for (int r = 0; r < 4; ++r) {
          const float pre = acc[mi][ni][r] + bias[ni];
          if (gi == 0) {                       // c-gate: g = tanh
            R[mi][ni][r] = tanh_f(pre);
          } else if (gi == 1) {                // i-gate
            R[mi][ni][r] *= sigmoid_f(pre);
          } else if (gi == 2) {                // f-gate: R = c = f*cf + i*g
            R[mi][ni][r] += sigmoid_f(pre) * cf;
          } else {                             // o-gate: h = sigmoid(o) * c
            const float h = sigmoid_f(pre) * R[mi][ni][r];
            const int row = bm + wm + mi * 16 + quad * 4 + r;
            const int col = bn + wn + ni * 16 + m16;
            out[(size_t)row * DOUT + col] = h;
          }
        }
      }
    }
    if (gi == 2) {  // write c
#pragma unroll
      for (int mi = 0; mi < 4; ++mi)
#pragma unroll
        for (int ni = 0; ni < 4; ++ni)
#pragma unroll
          for (int r = 0; r < 4; ++r) {
            const int row = bm + wm + mi * 16 + quad * 4 + r;
            const int col = bn + wn + ni * 16 + m16;
            out[(size_t)(B_ROWS * DOUT) + (size_t)row * DOUT + col] = R[mi][ni][r];
          }
    }
  }
}

extern "C" void kernel_launch(void* const* d_in, const int* in_sizes, int n_in,
                              void* d_out, int out_size, void* d_ws, size_t ws_size,
                              hipStream_t stream) {
  const float* inputs = (const float*)d_in[0];
  const float* hist   = (const float*)d_in[1];
  const int* carousel = (const int*)d_in[2];
  const float* Wfx = (const float*)d_in[3];
  const float* Wfh = (const float*)d_in[4];
  const float* bfv = (const float*)d_in[5];
  const float* Wix = (const float*)d_in[6];
  const float* Wih = (const float*)d_in[7];
  const float* biv = (const float*)d_in[8];
  const float* Wox = (const float*)d_in[9];
  const float* Woh = (const float*)d_in[10];
  const float* bov = (const float*)d_in[11];
  const float* Wcx = (const float*)d_in[12];
  const float* Wch = (const float*)d_in[13];
  const float* bcv = (const float*)d_in[14];

  unsigned short* Xb = (unsigned short*)d_ws;                    // 16384 x 2048 bf16 (64 MB)
  unsigned short* Wt = Xb + (size_t)B_ROWS * KDIM;               // 4 x 1024 x 2048 bf16 (16 MB)

  {
    const int total = 2 * B_ROWS * DIN / 4;
    cast_x_kernel<<<total / 256, 256, 0, stream>>>(inputs, hist, Xb);
  }
  {
    dim3 grid(DOUT / 32, DIN / 32, 8);
    dim3 block(32, 8);
    transpose_cast_kernel<<<grid, block, 0, stream>>>(
        Wfx, Wfh, Wix, Wih, Wox, Woh, Wcx, Wch, Wt);
  }
  {
    dim3 grid(DOUT / BN, B_ROWS / BM);
    lstm_fused_kernel<<<grid, 256, 0, stream>>>(
        Xb, Wt, bfv, biv, bov, bcv, carousel, (float*)d_out);
  }
}

// Round 2
// 650.893 us; speedup vs baseline: 1.1032x; 1.1032x over previous
//
#include <hip/hip_runtime.h>
#include <stdint.h>
#include <stddef.h>

#define B_ROWS 16384
#define DIN 1024
#define DOUT 1024
#define KDIM 2048   // DIN + DOUT

#define BM 128
#define BN 128
#define BK 64

typedef __bf16 bf16x8 __attribute__((ext_vector_type(8)));
typedef float floatx4 __attribute__((ext_vector_type(4)));

__device__ __forceinline__ unsigned short f2bf(float f) {
  unsigned int u = __float_as_uint(f);
  u += 0x7fffu + ((u >> 16) & 1u);   // round-to-nearest-even
  return (unsigned short)(u >> 16);
}

__device__ __forceinline__ void async16(const void* g, void* l) {
  __builtin_amdgcn_global_load_lds(
      (__attribute__((address_space(1))) void*)(g),
      (__attribute__((address_space(3))) void*)(l), 16, 0, 0);
}

__device__ __forceinline__ float sigmoid_f(float x) {
  return 1.0f / (1.0f + __expf(-x));
}
__device__ __forceinline__ float tanh_f(float x) {
  return 2.0f / (1.0f + __expf(-2.0f * x)) - 1.0f;
}

// ---- cast & concat X = [inputs | hist] -> bf16, row-major 16384 x 2048 ----
__global__ void cast_x_kernel(const float* __restrict__ inp,
                              const float* __restrict__ hist,
                              unsigned short* __restrict__ xb) {
  int idx = blockIdx.x * blockDim.x + threadIdx.x;  // one float4 per thread
  const int per = B_ROWS * DIN / 4;                 // 4,194,304
  const float* src;
  int colOff;
  int i = idx;
  if (i < per) { src = inp; colOff = 0; }
  else         { src = hist; colOff = DIN; i -= per; }
  int e = i * 4;
  int row = e >> 10;     // / 1024
  int col = e & 1023;
  const float4 v = *(const float4*)(src + (size_t)row * 1024 + col);
  ushort4 o;
  o.x = f2bf(v.x); o.y = f2bf(v.y); o.z = f2bf(v.z); o.w = f2bf(v.w);
  *(ushort4*)(xb + (size_t)row * KDIM + colOff + col) = o;
}

// ---- cast & transpose weights: Wt[g][n][k] = W_g[k][n], bf16 ----
// z = 2*g + part ; part0 = Wx (k in 0..1023), part1 = Wh (k in 1024..2047)
__global__ void transpose_cast_kernel(
    const float* __restrict__ s0, const float* __restrict__ s1,
    const float* __restrict__ s2, const float* __restrict__ s3,
    const float* __restrict__ s4, const float* __restrict__ s5,
    const float* __restrict__ s6, const float* __restrict__ s7,
    unsigned short* __restrict__ wt) {
  __shared__ float tile[32][33];
  const int z = blockIdx.z;
  const float* src;
  switch (z) {
    case 0: src = s0; break; case 1: src = s1; break;
    case 2: src = s2; break; case 3: src = s3; break;
    case 4: src = s4; break; case 5: src = s5; break;
    case 6: src = s6; break; default: src = s7; break;
  }
  const int g = z >> 1, part = z & 1;
  unsigned short* dst = wt + (size_t)g * DOUT * KDIM + (size_t)part * DIN;
  const int tx = threadIdx.x, ty = threadIdx.y;   // 32 x 8
  const int n0 = blockIdx.x * 32, k0 = blockIdx.y * 32;
#pragma unroll
  for (int j = 0; j < 32; j += 8)
    tile[ty + j][tx] = src[(size_t)(k0 + ty + j) * DOUT + n0 + tx];
  __syncthreads();
#pragma unroll
  for (int j = 0; j < 32; j += 8)
    dst[(size_t)(n0 + ty + j) * KDIM + k0 + tx] = f2bf(tile[tx][ty + j]);
}

// ---- fused 4-gate GEMM + LSTM epilogue ----
// LDS layout XOR-swizzle: slot (row, t) holds global k-chunk (row, t ^ (row&7)).
// global_load_lds requires LDS dest = wave-uniform base + lane*16, so we
// permute the GLOBAL source chunk per slot instead of padding the row stride.
// Reader: chunk c of row r lives at slot c ^ (r&7)  -> 8 lanes per 4-bank
// group per wave read -> conflict-free (was 16-way: row stride 128B = 32 banks).
__global__ __launch_bounds__(256, 2) void lstm_fused_kernel(
    const unsigned short* __restrict__ Xb,   // 16384 x 2048 bf16
    const unsigned short* __restrict__ Wt,   // 4 x (1024 x 2048) bf16, [g][n][k]
    const float* __restrict__ b_f, const float* __restrict__ b_i,
    const float* __restrict__ b_o, const float* __restrict__ b_c,
    const int* __restrict__ carousel,
    float* __restrict__ out) {               // h (16384x1024) then c
  __shared__ unsigned short As[BM * BK];
  __shared__ unsigned short Bs[BN * BK];

  const int tid  = threadIdx.x;
  const int lane = tid & 63;
  const int wave = tid >> 6;
  const int wm   = (wave >> 1) * 64;
  const int wn   = (wave & 1) * 64;
  const int m16  = lane & 15;
  const int quad = lane >> 4;
  const int r7   = m16 & 7;          // row&7 for all fragment rows this lane reads
  const int bm   = blockIdx.y * BM;
  const int bn   = blockIdx.x * BN;

  const float cf = (float)carousel[0];

  floatx4 R[4][4];
#pragma unroll
  for (int mi = 0; mi < 4; ++mi)
#pragma unroll
    for (int ni = 0; ni < 4; ++ni)
      R[mi][ni] = (floatx4){0.f, 0.f, 0.f, 0.f};

  // gate memory index: f=0, i=1, o=2, c=3 ; process order: c, i, f, o
  const int gates[4] = {3, 1, 0, 2};
  const float* bptrs[4] = {b_c, b_i, b_f, b_o};

  // staging indices (swizzled global source chunk per LDS slot)
  int srow[4], scol[4];
#pragma unroll
  for (int j = 0; j < 4; ++j) {
    const int c = j * 256 + tid;
    srow[j] = c >> 3;
    scol[j] = (c & 7) ^ (srow[j] & 7);   // global chunk index to fetch
  }

#pragma unroll
  for (int gi = 0; gi < 4; ++gi) {
    const int g = gates[gi];
    const unsigned short* W = Wt + (size_t)g * (DOUT * KDIM);

    floatx4 acc[4][4];
#pragma unroll
    for (int mi = 0; mi < 4; ++mi)
#pragma unroll
      for (int ni = 0; ni < 4; ++ni)
        acc[mi][ni] = (floatx4){0.f, 0.f, 0.f, 0.f};

    for (int kt = 0; kt < KDIM; kt += BK) {
#pragma unroll
      for (int j = 0; j < 4; ++j) {
        const int c = j * 256 + tid;
        async16(Xb + (size_t)(bm + srow[j]) * KDIM + kt + scol[j] * 8, As + c * 8);
      }
#pragma unroll
      for (int j = 0; j < 4; ++j) {
        const int c = j * 256 + tid;
        async16(W + (size_t)(bn + srow[j]) * KDIM + kt + scol[j] * 8, Bs + c * 8);
      }
      __syncthreads();
#pragma unroll
      for (int kk = 0; kk < 2; ++kk) {
        bf16x8 av[4], bv[4];
#pragma unroll
        for (int mi = 0; mi < 4; ++mi) {
          const int row = wm + mi * 16 + m16;
          const int t = (kk * 4 + quad) ^ r7;    // swizzled slot
          av[mi] = *(const bf16x8*)(As + row * BK + t * 8);
        }
#pragma unroll
        for (int ni = 0; ni < 4; ++ni) {
          const int row = wn + ni * 16 + m16;
          const int t = (kk * 4 + quad) ^ r7;
          bv[ni] = *(const bf16x8*)(Bs + row * BK + t * 8);
        }
#pragma unroll
        for (int mi = 0; mi < 4; ++mi)
#pragma unroll
          for (int ni = 0; ni < 4; ++ni)
            acc[mi][ni] = __builtin_amdgcn_mfma_f32_16x16x32_bf16(
                av[mi], bv[ni], acc[mi][ni], 0, 0, 0);
      }
      __syncthreads();
    }

    // epilogue for this gate
    const float* bp = bptrs[gi];
    float bias[4];
#pragma unroll
    for (int ni = 0; ni < 4; ++ni) bias[ni] = bp[bn + wn + ni * 16 + m16];

#pragma unroll
    for (int mi = 0; mi < 4; ++mi) {
#pragma unroll
      for (int ni = 0; ni < 4; ++ni) {
#pragma unroll
        for (int r = 0; r < 4; ++r) {
          const float pre = acc[mi][ni][r] + bias[ni];
          if (gi == 0) {                       // c-gate: g = tanh
            R[mi][ni][r] = tanh_f(pre);
          } else if (gi == 1) {                // i-gate
            R[mi][ni][r] *= sigmoid_f(pre);
          } else if (gi == 2) {                // f-gate: R = c = f*cf + i*g
            R[mi][ni][r] += sigmoid_f(pre) * cf;
          } else {                             // o-gate: h = sigmoid(o) * c
            const float h = sigmoid_f(pre) * R[mi][ni][r];
            const int row = bm + wm + mi * 16 + quad * 4 + r;
            const int col = bn + wn + ni * 16 + m16;
            out[(size_t)row * DOUT + col] = h;
          }
        }
      }
    }
    if (gi == 2) {  // write c
#pragma unroll
      for (int mi = 0; mi < 4; ++mi)
#pragma unroll
        for (int ni = 0; ni < 4; ++ni)
#pragma unroll
          for (int r = 0; r < 4; ++r) {
            const int row = bm + wm + mi * 16 + quad * 4 + r;
            const int col = bn + wn + ni * 16 + m16;
            out[(size_t)(B_ROWS * DOUT) + (size_t)row * DOUT + col] = R[mi][ni][r];
          }
    }
  }
}

extern "C" void kernel_launch(void* const* d_in, const int* in_sizes, int n_in,
                              void* d_out, int out_size, void* d_ws, size_t ws_size,
                              hipStream_t stream) {
  const float* inputs = (const float*)d_in[0];
  const float* hist   = (const float*)d_in[1];
  const int* carousel = (const int*)d_in[2];
  const float* Wfx = (const float*)d_in[3];
  const float* Wfh = (const float*)d_in[4];
  const float* bfv = (const float*)d_in[5];
  const float* Wix = (const float*)d_in[6];
  const float* Wih = (const float*)d_in[7];
  const float* biv = (const float*)d_in[8];
  const float* Wox = (const float*)d_in[9];
  const float* Woh = (const float*)d_in[10];
  const float* bov = (const float*)d_in[11];
  const float* Wcx = (const float*)d_in[12];
  const float* Wch = (const float*)d_in[13];
  const float* bcv = (const float*)d_in[14];

  unsigned short* Xb = (unsigned short*)d_ws;                    // 16384 x 2048 bf16 (64 MB)
  unsigned short* Wt = Xb + (size_t)B_ROWS * KDIM;               // 4 x 1024 x 2048 bf16 (16 MB)

  {
    const int total = 2 * B_ROWS * DIN / 4;
    cast_x_kernel<<<total / 256, 256, 0, stream>>>(inputs, hist, Xb);
  }
  {
    dim3 grid(DOUT / 32, DIN / 32, 8);
    dim3 block(32, 8);
    transpose_cast_kernel<<<grid, block, 0, stream>>>(
        Wfx, Wfh, Wix, Wih, Wox, Woh, Wcx, Wch, Wt);
  }
  {
    dim3 grid(DOUT / BN, B_ROWS / BM);
    lstm_fused_kernel<<<grid, 256, 0, stream>>>(
        Xb, Wt, bfv, biv, bov, bcv, carousel, (float*)d_out);
  }
}

// Round 3
// 524.432 us; speedup vs baseline: 1.3692x; 1.2411x over previous
//
#include <hip/hip_runtime.h>
#include <stdint.h>
#include <stddef.h>

#define B_ROWS 16384
#define DIN 1024
#define DOUT 1024
#define KDIM 2048   // DIN + DOUT

#define BM 128
#define BNP 128     // packed N per block = 4 gates x 32 cols
#define BK 64

typedef __bf16 bf16x8 __attribute__((ext_vector_type(8)));
typedef float floatx4 __attribute__((ext_vector_type(4)));

__device__ __forceinline__ unsigned short f2bf(float f) {
  unsigned int u = __float_as_uint(f);
  u += 0x7fffu + ((u >> 16) & 1u);   // round-to-nearest-even
  return (unsigned short)(u >> 16);
}

__device__ __forceinline__ void async16(const void* g, void* l) {
  __builtin_amdgcn_global_load_lds(
      (__attribute__((address_space(1))) void*)(g),
      (__attribute__((address_space(3))) void*)(l), 16, 0, 0);
}

__device__ __forceinline__ float sigmoid_f(float x) {
  return 1.0f / (1.0f + __expf(-x));
}
__device__ __forceinline__ float tanh_f(float x) {
  return 2.0f / (1.0f + __expf(-2.0f * x)) - 1.0f;
}

// ---- cast & concat X = [inputs | hist] -> bf16, row-major 16384 x 2048 ----
__global__ void cast_x_kernel(const float* __restrict__ inp,
                              const float* __restrict__ hist,
                              unsigned short* __restrict__ xb) {
  int idx = blockIdx.x * blockDim.x + threadIdx.x;  // one float4 per thread
  const int per = B_ROWS * DIN / 4;
  const float* src;
  int colOff;
  int i = idx;
  if (i < per) { src = inp; colOff = 0; }
  else         { src = hist; colOff = DIN; i -= per; }
  int e = i * 4;
  int row = e >> 10;
  int col = e & 1023;
  const float4 v = *(const float4*)(src + (size_t)row * 1024 + col);
  ushort4 o;
  o.x = f2bf(v.x); o.y = f2bf(v.y); o.z = f2bf(v.z); o.w = f2bf(v.w);
  *(ushort4*)(xb + (size_t)row * KDIM + colOff + col) = o;
}

// ---- cast & transpose weights into gate-packed n-major layout ----
// Wt2 row index n' = (n>>5)*128 + g*32 + (n&31), row length KDIM (k-major).
// So one GEMM block (128 packed rows) = all 4 gates for the same 32 cols.
// z = 2*g + part ; part0 = Wx (k 0..1023), part1 = Wh (k 1024..2047)
// gate order g: 0=f 1=i 2=o 3=c
__global__ void transpose_cast_kernel(
    const float* __restrict__ s0, const float* __restrict__ s1,
    const float* __restrict__ s2, const float* __restrict__ s3,
    const float* __restrict__ s4, const float* __restrict__ s5,
    const float* __restrict__ s6, const float* __restrict__ s7,
    unsigned short* __restrict__ wt) {
  __shared__ float tile[32][33];
  const int z = blockIdx.z;
  const float* src;
  switch (z) {
    case 0: src = s0; break; case 1: src = s1; break;
    case 2: src = s2; break; case 3: src = s3; break;
    case 4: src = s4; break; case 5: src = s5; break;
    case 6: src = s6; break; default: src = s7; break;
  }
  const int g = z >> 1, part = z & 1;
  const int tx = threadIdx.x, ty = threadIdx.y;   // 32 x 8
  const int n0 = blockIdx.x * 32, k0 = blockIdx.y * 32;
#pragma unroll
  for (int j = 0; j < 32; j += 8)
    tile[ty + j][tx] = src[(size_t)(k0 + ty + j) * DOUT + n0 + tx];
  __syncthreads();
#pragma unroll
  for (int j = 0; j < 32; j += 8) {
    const int n = n0 + ty + j;
    const int np = (n >> 5) * 128 + g * 32 + (n & 31);
    wt[(size_t)np * KDIM + part * DIN + k0 + tx] = f2bf(tile[tx][ty + j]);
  }
}

// ---- single-pass 4-gate GEMM + LSTM epilogue ----
// Block: 128 rows x 32 output cols x 4 gates (packed N=128).
// Waves partition M: wave tile 32 x 128 -> 2 m-frags x 8 n-frags,
// ni -> gate = ni>>1, cs = ni&1; every thread holds f,i,o,c for the
// same (row,col) -> direct combine in epilogue, no persistent state.
// LDS XOR-swizzle as in R1: slot (row,t) holds global chunk t^(row&7).
__global__ __launch_bounds__(256, 3) void lstm_fused_kernel(
    const unsigned short* __restrict__ Xb,    // 16384 x 2048 bf16
    const unsigned short* __restrict__ Wt2,   // 4096 x 2048 bf16 packed
    const float* __restrict__ b_f, const float* __restrict__ b_i,
    const float* __restrict__ b_o, const float* __restrict__ b_c,
    const int* __restrict__ carousel,
    float* __restrict__ out) {                // h (16384x1024) then c
  __shared__ unsigned short As[BM * BK];
  __shared__ unsigned short Bs[BNP * BK];

  const int tid  = threadIdx.x;
  const int lane = tid & 63;
  const int wave = tid >> 6;
  const int wm   = wave * 32;
  const int m16  = lane & 15;
  const int quad = lane >> 4;
  const int r7   = m16 & 7;
  const int bm   = blockIdx.y * BM;
  const int cg   = blockIdx.x;              // 32-col output group

  const unsigned short* Wp = Wt2 + (size_t)cg * BNP * KDIM;

  floatx4 acc[2][8];
#pragma unroll
  for (int mi = 0; mi < 2; ++mi)
#pragma unroll
    for (int ni = 0; ni < 8; ++ni)
      acc[mi][ni] = (floatx4){0.f, 0.f, 0.f, 0.f};

  // staging indices (swizzled global source chunk per LDS slot)
  int srow[4], scol[4];
#pragma unroll
  for (int j = 0; j < 4; ++j) {
    const int c = j * 256 + tid;
    srow[j] = c >> 3;
    scol[j] = (c & 7) ^ (srow[j] & 7);
  }

  for (int kt = 0; kt < KDIM; kt += BK) {
#pragma unroll
    for (int j = 0; j < 4; ++j) {
      const int c = j * 256 + tid;
      async16(Xb + (size_t)(bm + srow[j]) * KDIM + kt + scol[j] * 8, As + c * 8);
    }
#pragma unroll
    for (int j = 0; j < 4; ++j) {
      const int c = j * 256 + tid;
      async16(Wp + (size_t)srow[j] * KDIM + kt + scol[j] * 8, Bs + c * 8);
    }
    __syncthreads();
#pragma unroll
    for (int kk = 0; kk < 2; ++kk) {
      const int t = (kk * 4 + quad) ^ r7;
      bf16x8 av[2], bv[8];
#pragma unroll
      for (int mi = 0; mi < 2; ++mi)
        av[mi] = *(const bf16x8*)(As + (wm + mi * 16 + m16) * BK + t * 8);
#pragma unroll
      for (int ni = 0; ni < 8; ++ni)
        bv[ni] = *(const bf16x8*)(Bs + (ni * 16 + m16) * BK + t * 8);
#pragma unroll
      for (int mi = 0; mi < 2; ++mi)
#pragma unroll
        for (int ni = 0; ni < 8; ++ni)
          acc[mi][ni] = __builtin_amdgcn_mfma_f32_16x16x32_bf16(
              av[mi], bv[ni], acc[mi][ni], 0, 0, 0);
    }
    __syncthreads();
  }

  // epilogue: combine gates, write h and c
  const float cf = (float)carousel[0];
  float bfv[2], biv[2], bov[2], bcv[2];
#pragma unroll
  for (int cs = 0; cs < 2; ++cs) {
    const int col = cg * 32 + cs * 16 + m16;
    bfv[cs] = b_f[col]; biv[cs] = b_i[col];
    bov[cs] = b_o[col]; bcv[cs] = b_c[col];
  }

#pragma unroll
  for (int mi = 0; mi < 2; ++mi) {
#pragma unroll
    for (int cs = 0; cs < 2; ++cs) {
      const int col = cg * 32 + cs * 16 + m16;
#pragma unroll
      for (int r = 0; r < 4; ++r) {
        const int row = bm + wm + mi * 16 + quad * 4 + r;
        const float f = sigmoid_f(acc[mi][0 + cs][r] + bfv[cs]);
        const float i = sigmoid_f(acc[mi][2 + cs][r] + biv[cs]);
        const float o = sigmoid_f(acc[mi][4 + cs][r] + bov[cs]);
        const float g = tanh_f   (acc[mi][6 + cs][r] + bcv[cs]);
        const float c = f * cf + i * g;
        const float h = o * c;
        out[(size_t)row * DOUT + col] = h;
        out[(size_t)(B_ROWS * DOUT) + (size_t)row * DOUT + col] = c;
      }
    }
  }
}

extern "C" void kernel_launch(void* const* d_in, const int* in_sizes, int n_in,
                              void* d_out, int out_size, void* d_ws, size_t ws_size,
                              hipStream_t stream) {
  const float* inputs = (const float*)d_in[0];
  const float* hist   = (const float*)d_in[1];
  const int* carousel = (const int*)d_in[2];
  const float* Wfx = (const float*)d_in[3];
  const float* Wfh = (const float*)d_in[4];
  const float* bfv = (const float*)d_in[5];
  const float* Wix = (const float*)d_in[6];
  const float* Wih = (const float*)d_in[7];
  const float* biv = (const float*)d_in[8];
  const float* Wox = (const float*)d_in[9];
  const float* Woh = (const float*)d_in[10];
  const float* bov = (const float*)d_in[11];
  const float* Wcx = (const float*)d_in[12];
  const float* Wch = (const float*)d_in[13];
  const float* bcv = (const float*)d_in[14];

  unsigned short* Xb  = (unsigned short*)d_ws;               // 64 MB
  unsigned short* Wt2 = Xb + (size_t)B_ROWS * KDIM;          // 16 MB

  {
    const int total = 2 * B_ROWS * DIN / 4;
    cast_x_kernel<<<total / 256, 256, 0, stream>>>(inputs, hist, Xb);
  }
  {
    dim3 grid(DOUT / 32, DIN / 32, 8);
    dim3 block(32, 8);
    transpose_cast_kernel<<<grid, block, 0, stream>>>(
        Wfx, Wfh, Wix, Wih, Wox, Woh, Wcx, Wch, Wt2);
  }
  {
    dim3 grid(DOUT / 32, B_ROWS / BM);
    lstm_fused_kernel<<<grid, 256, 0, stream>>>(
        Xb, Wt2, bfv, biv, bov, bcv, carousel, (float*)d_out);
  }
}